// Round 2
// baseline (316.845 us; speedup 1.0000x reference)
//
#include <hip/hip_runtime.h>
#include <hip/hip_bf16.h>

typedef __bf16 bf16x8 __attribute__((ext_vector_type(8)));
typedef __bf16 bf16x4 __attribute__((ext_vector_type(4)));
typedef float  f32x4  __attribute__((ext_vector_type(4)));

#define MFMA16(A,B,Cc) __builtin_amdgcn_mfma_f32_16x16x32_bf16(A,B,Cc,0,0,0)

// Load 8 contiguous elements as a bf16x8 fragment, converting if needed.
template<typename T> __device__ inline bf16x8 load8(const T* p);
template<> __device__ inline bf16x8 load8<__bf16>(const __bf16* p) {
  return *(const bf16x8*)p;
}
template<> __device__ inline bf16x8 load8<float>(const float* p) {
  const f32x4 a = *(const f32x4*)p;
  const f32x4 b = *(const f32x4*)(p + 4);
  bf16x8 r;
#pragma unroll
  for (int j = 0; j < 4; ++j) { r[j] = (__bf16)a[j]; r[j + 4] = (__bf16)b[j]; }
  return r;
}

// Dtype probe: reinterpret first 1024 uint16 of x as bf16. If the buffer is
// actually f32, odd halves are f32 mantissa bits -> ~42% have exponent>=0xC0.
// Genuine bf16 N(0,1) data never does. flag: 0 = f32 buffers, 1 = bf16.
__global__ void probe_kernel(const unsigned short* __restrict__ x, int* flag) {
  if (threadIdx.x == 0 && blockIdx.x == 0) {
    int huge = 0;
    for (int i = 0; i < 1024; ++i) {
      const int e = (x[i] >> 7) & 0xFF;
      if (e >= 0xC0) ++huge;
    }
    flag[0] = (huge > 0) ? 0 : 1;
  }
}

// out = A @ W^T + bias   (A: [4096][1024], W: [1024][1024], K contiguous)
// MODE 0: plain out[m][n] to TO* outp      ([4096][1024])
// MODE 1: Q/K scatter  [BH][T][D]  (bf16 ws)
// MODE 2: V^T scatter  [BH][D][T]  (bf16 ws)
template<int MODE, typename TA, typename TW, typename TO>
__global__ __launch_bounds__(256) void gemm_bias_kernel(
    const TA* __restrict__ A, const TW* __restrict__ W,
    const TW* __restrict__ bias, TO* __restrict__ outp,
    __bf16* __restrict__ outw, const int* __restrict__ flag, int want)
{
  if (flag[0] != want) return;

  __shared__ __align__(16) __bf16 As[128 * 32];
  __shared__ __align__(16) __bf16 Bs[128 * 32];
  const int tid  = threadIdx.x;
  const int lane = tid & 63;
  const int wv   = tid >> 6;
  const int wr   = wv >> 1, wc = wv & 1;      // 2x2 waves, 64x64 each
  const int m0   = blockIdx.y * 128, n0 = blockIdx.x * 128;
  const int g    = lane >> 4, cl = lane & 15;

  const int sr = tid >> 2;            // staging row 0..63 (and +64)
  const int sk = (tid & 3) * 8;       // staging k-offset

  f32x4 acc[4][4] = {};

  for (int k0 = 0; k0 < 1024; k0 += 32) {
    bf16x8 a0 = load8<TA>(A + (size_t)(m0 + sr)      * 1024 + k0 + sk);
    bf16x8 a1 = load8<TA>(A + (size_t)(m0 + sr + 64) * 1024 + k0 + sk);
    bf16x8 b0 = load8<TW>(W + (size_t)(n0 + sr)      * 1024 + k0 + sk);
    bf16x8 b1 = load8<TW>(W + (size_t)(n0 + sr + 64) * 1024 + k0 + sk);
    __syncthreads();
    *(bf16x8*)(As + sr * 32 + sk)        = a0;
    *(bf16x8*)(As + (sr + 64) * 32 + sk) = a1;
    *(bf16x8*)(Bs + sr * 32 + sk)        = b0;
    *(bf16x8*)(Bs + (sr + 64) * 32 + sk) = b1;
    __syncthreads();
    bf16x8 af[4], bfr[4];
#pragma unroll
    for (int m = 0; m < 4; ++m)
      af[m] = *(const bf16x8*)(As + (wr * 64 + m * 16 + cl) * 32 + g * 8);
#pragma unroll
    for (int n = 0; n < 4; ++n)
      bfr[n] = *(const bf16x8*)(Bs + (wc * 64 + n * 16 + cl) * 32 + g * 8);
#pragma unroll
    for (int m = 0; m < 4; ++m)
#pragma unroll
      for (int n = 0; n < 4; ++n)
        acc[m][n] = MFMA16(af[m], bfr[n], acc[m][n]);
  }

  float bv[4];
#pragma unroll
  for (int n = 0; n < 4; ++n) bv[n] = (float)bias[n0 + wc * 64 + n * 16 + cl];

#pragma unroll
  for (int m = 0; m < 4; ++m) {
#pragma unroll
    for (int n = 0; n < 4; ++n) {
      const int col = n0 + wc * 64 + n * 16 + cl;
      if (MODE == 2) {
        const int row0 = m0 + wr * 64 + m * 16 + g * 4;
        bf16x4 v4;
#pragma unroll
        for (int j = 0; j < 4; ++j) v4[j] = (__bf16)(acc[m][n][j] + bv[n]);
        const int b = row0 >> 11, t = row0 & 2047, h = col >> 6, d = col & 63;
        *(bf16x4*)(outw + (size_t)(b * 16 + h) * 131072 + d * 2048 + t) = v4;
      } else {
#pragma unroll
        for (int j = 0; j < 4; ++j) {
          const int row = m0 + wr * 64 + m * 16 + g * 4 + j;
          const float v = acc[m][n][j] + bv[n];
          if (MODE == 0) {
            outp[(size_t)row * 1024 + col] = (TO)v;
          } else {
            const int b = row >> 11, t = row & 2047, h = col >> 6, d = col & 63;
            outw[(size_t)(b * 16 + h) * 131072 + (size_t)t * 64 + d] = (__bf16)v;
          }
        }
      }
    }
  }
}

// Causal flash attention (dtype-agnostic: all operands are ws bf16 buffers).
// Q,K: [BH][T][64]; Vt: [BH][64][T]; Aw: [4096][1024] row-major (b*T+t, h*64+d).
__global__ __launch_bounds__(256) void attn_kernel(
    const __bf16* __restrict__ Q, const __bf16* __restrict__ K,
    const __bf16* __restrict__ Vt, __bf16* __restrict__ Oc)
{
  const int bh   = blockIdx.x;
  const int wv   = threadIdx.x >> 6;
  const int lane = threadIdx.x & 63;
  const int g = lane >> 4, cl = lane & 15;
  const int qs = blockIdx.y * 64 + wv * 16;   // wave's q-strip start

  const __bf16* Qb = Q  + (size_t)bh * 131072;
  const __bf16* Kb = K  + (size_t)bh * 131072;
  const __bf16* Vb = Vt + (size_t)bh * 131072;

  __shared__ __align__(16) __bf16 Pl[4][16 * 32];   // per-wave P tile
  __bf16* Pw = &Pl[wv][0];

  const bf16x8 qf0 = *(const bf16x8*)(Qb + (qs + cl) * 64 + g * 8);
  const bf16x8 qf1 = *(const bf16x8*)(Qb + (qs + cl) * 64 + 32 + g * 8);

  float M[4], L[4];
  f32x4 o[4] = {};
#pragma unroll
  for (int j = 0; j < 4; ++j) { M[j] = -1e30f; L[j] = 0.f; }

  const int nkb = (qs + 47) >> 5;             // k-blocks of 32, covers diag
  for (int kb = 0; kb < nkb; ++kb) {
    const int k0 = kb * 32;
    f32x4 s[2] = {};
#pragma unroll
    for (int kc = 0; kc < 2; ++kc) {
      bf16x8 kf0 = *(const bf16x8*)(Kb + (k0 + kc * 16 + cl) * 64 + g * 8);
      bf16x8 kf1 = *(const bf16x8*)(Kb + (k0 + kc * 16 + cl) * 64 + 32 + g * 8);
      s[kc] = MFMA16(qf0, kf0, s[kc]);
      s[kc] = MFMA16(qf1, kf1, s[kc]);
    }
    float sv[2][4];
#pragma unroll
    for (int kc = 0; kc < 2; ++kc)
#pragma unroll
      for (int j = 0; j < 4; ++j) {
        const int colk = k0 + kc * 16 + cl;
        const int rowq = qs + g * 4 + j;
        sv[kc][j] = (colk <= rowq) ? s[kc][j] * 0.125f : -1e30f;
      }
    float mt[4];
#pragma unroll
    for (int j = 0; j < 4; ++j) mt[j] = fmaxf(sv[0][j], sv[1][j]);
#pragma unroll
    for (int msk = 1; msk <= 8; msk <<= 1)
#pragma unroll
      for (int j = 0; j < 4; ++j) mt[j] = fmaxf(mt[j], __shfl_xor(mt[j], msk, 64));
    float rsc[4];
#pragma unroll
    for (int j = 0; j < 4; ++j) {
      const float Mn = fmaxf(M[j], mt[j]);
      rsc[j] = exp2f((M[j] - Mn) * 1.44269504f);
      M[j] = Mn;
    }
    float p[2][4], lt[4];
#pragma unroll
    for (int kc = 0; kc < 2; ++kc)
#pragma unroll
      for (int j = 0; j < 4; ++j)
        p[kc][j] = exp2f((sv[kc][j] - M[j]) * 1.44269504f);
#pragma unroll
    for (int j = 0; j < 4; ++j) lt[j] = p[0][j] + p[1][j];
#pragma unroll
    for (int msk = 1; msk <= 8; msk <<= 1)
#pragma unroll
      for (int j = 0; j < 4; ++j) lt[j] += __shfl_xor(lt[j], msk, 64);
#pragma unroll
    for (int j = 0; j < 4; ++j) L[j] = L[j] * rsc[j] + lt[j];
#pragma unroll
    for (int dt = 0; dt < 4; ++dt)
#pragma unroll
      for (int j = 0; j < 4; ++j) o[dt][j] *= rsc[j];
    // P (C-layout) -> LDS -> A-fragment layout (wave-local round-trip)
#pragma unroll
    for (int kc = 0; kc < 2; ++kc)
#pragma unroll
      for (int j = 0; j < 4; ++j)
        Pw[(g * 4 + j) * 32 + kc * 16 + cl] = (__bf16)p[kc][j];
    asm volatile("s_waitcnt lgkmcnt(0)" ::: "memory");
    __builtin_amdgcn_sched_barrier(0);
    const bf16x8 pf = *(const bf16x8*)(Pw + cl * 32 + g * 8);
#pragma unroll
    for (int dt = 0; dt < 4; ++dt) {
      bf16x8 vf = *(const bf16x8*)(Vb + (dt * 16 + cl) * 2048 + k0 + g * 8);
      o[dt] = MFMA16(pf, vf, o[dt]);
    }
  }

  const int b = bh >> 4, h = bh & 15;
#pragma unroll
  for (int dt = 0; dt < 4; ++dt)
#pragma unroll
    for (int j = 0; j < 4; ++j) {
      const int t = qs + g * 4 + j;
      Oc[(size_t)(b * 2048 + t) * 1024 + h * 64 + dt * 16 + cl] =
          (__bf16)(o[dt][j] / L[j]);
    }
}

extern "C" void kernel_launch(void* const* d_in, const int* in_sizes, int n_in,
                              void* d_out, int out_size, void* d_ws, size_t ws_size,
                              hipStream_t stream) {
  // flag in first 256 bytes of ws; bf16 buffers after.
  int*    flag = (int*)d_ws;
  __bf16* base = (__bf16*)((char*)d_ws + 256);
  __bf16* Qw = base;                          // [32][2048][64]  8 MB
  __bf16* Kw = Qw + (size_t)4194304;          // [32][2048][64]  8 MB
  __bf16* Vw = Kw + (size_t)4194304;          // [32][64][2048]  8 MB (V^T)
  __bf16* Aw = Vw + (size_t)4194304;          // [4096][1024]    8 MB (attn out)

  dim3 gg(8, 32), bb(256);

  probe_kernel<<<1, 64, 0, stream>>>((const unsigned short*)d_in[0], flag);

  // f32-input pipeline (want=0)
  {
    const float* x  = (const float*)d_in[0];
    const float* Wq = (const float*)d_in[1];
    const float* bq = (const float*)d_in[2];
    const float* Wk = (const float*)d_in[3];
    const float* bk = (const float*)d_in[4];
    const float* Wv = (const float*)d_in[5];
    const float* bv = (const float*)d_in[6];
    gemm_bias_kernel<1, float, float, float><<<gg, bb, 0, stream>>>(
        x, Wq, bq, (float*)nullptr, Qw, flag, 0);
    gemm_bias_kernel<1, float, float, float><<<gg, bb, 0, stream>>>(
        x, Wk, bk, (float*)nullptr, Kw, flag, 0);
    gemm_bias_kernel<2, float, float, float><<<gg, bb, 0, stream>>>(
        x, Wv, bv, (float*)nullptr, Vw, flag, 0);
  }
  // bf16-input pipeline (want=1)
  {
    const __bf16* x  = (const __bf16*)d_in[0];
    const __bf16* Wq = (const __bf16*)d_in[1];
    const __bf16* bq = (const __bf16*)d_in[2];
    const __bf16* Wk = (const __bf16*)d_in[3];
    const __bf16* bk = (const __bf16*)d_in[4];
    const __bf16* Wv = (const __bf16*)d_in[5];
    const __bf16* bv = (const __bf16*)d_in[6];
    gemm_bias_kernel<1, __bf16, __bf16, __bf16><<<gg, bb, 0, stream>>>(
        x, Wq, bq, (__bf16*)nullptr, Qw, flag, 1);
    gemm_bias_kernel<1, __bf16, __bf16, __bf16><<<gg, bb, 0, stream>>>(
        x, Wk, bk, (__bf16*)nullptr, Kw, flag, 1);
    gemm_bias_kernel<2, __bf16, __bf16, __bf16><<<gg, bb, 0, stream>>>(
        x, Wv, bv, (__bf16*)nullptr, Vw, flag, 1);
  }

  attn_kernel<<<dim3(32, 32), bb, 0, stream>>>(Qw, Kw, Vw, Aw);

  // Final projection: out = Aw @ Wp^T + bp, output dtype matches input dtype.
  gemm_bias_kernel<0, __bf16, float, float><<<gg, bb, 0, stream>>>(
      Aw, (const float*)d_in[7], (const float*)d_in[8],
      (float*)d_out, (__bf16*)nullptr, flag, 0);
  gemm_bias_kernel<0, __bf16, __bf16, __bf16><<<gg, bb, 0, stream>>>(
      Aw, (const __bf16*)d_in[7], (const __bf16*)d_in[8],
      (__bf16*)d_out, (__bf16*)nullptr, flag, 1);
}

// Round 3
// 199.429 us; speedup vs baseline: 1.5888x; 1.5888x over previous
//
#include <hip/hip_runtime.h>
#include <hip/hip_bf16.h>

typedef __bf16 bf16x8 __attribute__((ext_vector_type(8)));
typedef __bf16 bf16x4 __attribute__((ext_vector_type(4)));
typedef __bf16 bf16x2 __attribute__((ext_vector_type(2)));
typedef float  f32x4  __attribute__((ext_vector_type(4)));
typedef float  f32x16v __attribute__((ext_vector_type(16)));

#define MFMA16(A,B,Cc) __builtin_amdgcn_mfma_f32_16x16x32_bf16(A,B,Cc,0,0,0)
#define MFMA32(A,B,Cc) __builtin_amdgcn_mfma_f32_32x32x16_bf16(A,B,Cc,0,0,0)

__device__ inline bf16x8 load8f(const float* p) {
  const f32x4 a = *(const f32x4*)p;
  const f32x4 b = *(const f32x4*)(p + 4);
  bf16x8 r;
#pragma unroll
  for (int j = 0; j < 4; ++j) { r[j] = (__bf16)a[j]; r[j + 4] = (__bf16)b[j]; }
  return r;
}

__device__ inline unsigned pack2(float a, float b) {
  union { bf16x2 v; unsigned u; } t;
  t.v[0] = (__bf16)a; t.v[1] = (__bf16)b;
  return t.u;
}
__device__ inline bf16x8 frag4(unsigned w0, unsigned w1, unsigned w2, unsigned w3) {
  union { unsigned u[4]; bf16x8 v; } t;
  t.u[0] = w0; t.u[1] = w1; t.u[2] = w2; t.u[3] = w3;
  return t.v;
}

// ---------------- fused QKV GEMM:  out_z = x @ Wz^T + bz ----------------
// x: [4096][1024] f32.  z=0,1 -> Q/K scatter [BH][T][64]; z=2 -> V^T [BH][64][T].
__global__ __launch_bounds__(256) void gemm_qkv_kernel(
    const float* __restrict__ x,
    const float* __restrict__ Wq, const float* __restrict__ bq,
    const float* __restrict__ Wk, const float* __restrict__ bk,
    const float* __restrict__ Wv, const float* __restrict__ bv,
    __bf16* __restrict__ Qw, __bf16* __restrict__ Kw, __bf16* __restrict__ Vw)
{
  __shared__ __align__(16) __bf16 As[64 * 40];   // +8 pad: kills 8-way read conflict
  __shared__ __align__(16) __bf16 Bs[64 * 40];
  const int z = blockIdx.z;
  const float* W  = (z == 0) ? Wq : (z == 1) ? Wk : Wv;
  const float* bi = (z == 0) ? bq : (z == 1) ? bk : bv;
  __bf16* out     = (z == 0) ? Qw : (z == 1) ? Kw : Vw;

  const int tid = threadIdx.x, lane = tid & 63, wid = tid >> 6;
  const int wr = wid >> 1, wc = wid & 1;
  const int g = lane >> 4, cl = lane & 15;
  const int m0 = blockIdx.y * 64, n0 = blockIdx.x * 64;
  const int sr = tid >> 2, sk = (tid & 3) * 8;

  f32x4 acc[2][2] = {};
  for (int k0 = 0; k0 < 1024; k0 += 32) {
    bf16x8 a = load8f(x + (size_t)(m0 + sr) * 1024 + k0 + sk);
    bf16x8 b = load8f(W + (size_t)(n0 + sr) * 1024 + k0 + sk);
    __syncthreads();
    *(bf16x8*)(As + sr * 40 + sk) = a;
    *(bf16x8*)(Bs + sr * 40 + sk) = b;
    __syncthreads();
    bf16x8 af[2], bfr[2];
#pragma unroll
    for (int m = 0; m < 2; ++m)
      af[m] = *(const bf16x8*)(As + (wr * 32 + m * 16 + cl) * 40 + g * 8);
#pragma unroll
    for (int n = 0; n < 2; ++n)
      bfr[n] = *(const bf16x8*)(Bs + (wc * 32 + n * 16 + cl) * 40 + g * 8);
#pragma unroll
    for (int m = 0; m < 2; ++m)
#pragma unroll
      for (int n = 0; n < 2; ++n)
        acc[m][n] = MFMA16(af[m], bfr[n], acc[m][n]);
  }

  float bvv[2];
#pragma unroll
  for (int n = 0; n < 2; ++n) bvv[n] = bi[n0 + wc * 32 + n * 16 + cl];

#pragma unroll
  for (int m = 0; m < 2; ++m)
#pragma unroll
    for (int n = 0; n < 2; ++n) {
      const int col = n0 + wc * 32 + n * 16 + cl;
      const int h = col >> 6, d = col & 63;
      if (z == 2) {
        const int row0 = m0 + wr * 32 + m * 16 + g * 4;
        const int b2 = row0 >> 11, t0 = row0 & 2047;
        bf16x4 v4;
#pragma unroll
        for (int j = 0; j < 4; ++j) v4[j] = (__bf16)(acc[m][n][j] + bvv[n]);
        *(bf16x4*)(out + (size_t)(b2 * 16 + h) * 131072 + (size_t)d * 2048 + t0) = v4;
      } else {
#pragma unroll
        for (int j = 0; j < 4; ++j) {
          const int row = m0 + wr * 32 + m * 16 + g * 4 + j;
          const int b2 = row >> 11, t = row & 2047;
          out[(size_t)(b2 * 16 + h) * 131072 + (size_t)t * 64 + d] =
              (__bf16)(acc[m][n][j] + bvv[n]);
        }
      }
    }
}

// ---------------- projection GEMM: out = Aw @ Wp^T + bp (f32 out) ----------------
__global__ __launch_bounds__(256) void gemm_proj_kernel(
    const __bf16* __restrict__ A, const float* __restrict__ W,
    const float* __restrict__ bi, float* __restrict__ outp)
{
  __shared__ __align__(16) __bf16 As[64 * 40];
  __shared__ __align__(16) __bf16 Bs[64 * 40];
  const int tid = threadIdx.x, lane = tid & 63, wid = tid >> 6;
  const int wr = wid >> 1, wc = wid & 1;
  const int g = lane >> 4, cl = lane & 15;
  const int m0 = blockIdx.y * 64, n0 = blockIdx.x * 64;
  const int sr = tid >> 2, sk = (tid & 3) * 8;

  f32x4 acc[2][2] = {};
  for (int k0 = 0; k0 < 1024; k0 += 32) {
    bf16x8 a = *(const bf16x8*)(A + (size_t)(m0 + sr) * 1024 + k0 + sk);
    bf16x8 b = load8f(W + (size_t)(n0 + sr) * 1024 + k0 + sk);
    __syncthreads();
    *(bf16x8*)(As + sr * 40 + sk) = a;
    *(bf16x8*)(Bs + sr * 40 + sk) = b;
    __syncthreads();
    bf16x8 af[2], bfr[2];
#pragma unroll
    for (int m = 0; m < 2; ++m)
      af[m] = *(const bf16x8*)(As + (wr * 32 + m * 16 + cl) * 40 + g * 8);
#pragma unroll
    for (int n = 0; n < 2; ++n)
      bfr[n] = *(const bf16x8*)(Bs + (wc * 32 + n * 16 + cl) * 40 + g * 8);
#pragma unroll
    for (int m = 0; m < 2; ++m)
#pragma unroll
      for (int n = 0; n < 2; ++n)
        acc[m][n] = MFMA16(af[m], bfr[n], acc[m][n]);
  }

  float bvv[2];
#pragma unroll
  for (int n = 0; n < 2; ++n) bvv[n] = bi[n0 + wc * 32 + n * 16 + cl];
#pragma unroll
  for (int m = 0; m < 2; ++m)
#pragma unroll
    for (int n = 0; n < 2; ++n) {
      const int col = n0 + wc * 32 + n * 16 + cl;
#pragma unroll
      for (int j = 0; j < 4; ++j) {
        const int row = m0 + wr * 32 + m * 16 + g * 4 + j;
        outp[(size_t)row * 1024 + col] = acc[m][n][j] + bvv[n];
      }
    }
}

// ---------------- causal flash attention, swapped-QK 32x32, LDS-free ----------------
// Q,K: [BH][T][64]; Vt: [BH][64][T]; Aw out: [B*T][1024] (h*64+d cols), all bf16.
// Wave = 32 q-rows; lane l: q = qs+(l&31); S^T via mfma(K,Q): lane holds 16 k-vals
// of its own q-row -> in-register softmax; cross-half combine via shfl_xor(32).
__global__ __launch_bounds__(256) void attn_kernel(
    const __bf16* __restrict__ Q, const __bf16* __restrict__ K,
    const __bf16* __restrict__ Vt, __bf16* __restrict__ Oc)
{
  const int bh  = blockIdx.x;
  const int wid = threadIdx.x >> 6;
  const int lane = threadIdx.x & 63;
  const int l31 = lane & 31, hi = lane >> 5;
  const int strip = 63 - (blockIdx.y * 4 + wid);   // long strips dispatch first
  const int qs = strip * 32;

  const __bf16* Qb = Q  + (size_t)bh * 131072;
  const __bf16* Kb = K  + (size_t)bh * 131072;
  const __bf16* Vb = Vt + (size_t)bh * 131072;

  bf16x8 qf[4];
#pragma unroll
  for (int c = 0; c < 4; ++c)
    qf[c] = *(const bf16x8*)(Qb + (qs + l31) * 64 + c * 16 + hi * 8);

  f32x16v o0 = {}, o1 = {};
  float M = -1e30f, L = 0.f;
  const float SC = 0.18033688f;   // 0.125 * log2(e)

  for (int kv0 = 0; kv0 <= qs; kv0 += 32) {
    // S^T = K Q^T over d (4 chunks of 16)
    f32x16v s = {};
#pragma unroll
    for (int c = 0; c < 4; ++c) {
      bf16x8 kf = *(const bf16x8*)(Kb + (kv0 + l31) * 64 + c * 16 + hi * 8);
      s = MFMA32(kf, qf[c], s);
    }
    float sv[16];
#pragma unroll
    for (int r = 0; r < 16; ++r) sv[r] = s[r];
    if (kv0 == qs) {             // diagonal tile: mask k > q
#pragma unroll
      for (int r = 0; r < 16; ++r) {
        const int kl = (r & 3) + 8 * (r >> 2) + 4 * hi;
        if (kl > l31) sv[r] = -1e30f;
      }
    }
    // row max: in-lane + cross-half
    float mt = sv[0];
#pragma unroll
    for (int r = 1; r < 16; ++r) mt = fmaxf(mt, sv[r]);
    mt = fmaxf(mt, __shfl_xor(mt, 32, 64));
    const float Mn = fmaxf(M, mt);
    const float rsc = exp2f((M - Mn) * SC);
    M = Mn;
    float p[16];
#pragma unroll
    for (int r = 0; r < 16; ++r) p[r] = exp2f((sv[r] - Mn) * SC);
    float lt = 0.f;
#pragma unroll
    for (int r = 0; r < 16; ++r) lt += p[r];
    lt += __shfl_xor(lt, 32, 64);
    L = L * rsc + lt;
#pragma unroll
    for (int r = 0; r < 16; ++r) { o0[r] *= rsc; o1[r] *= rsc; }

    // P^T B-fragments: pack bf16 pairs, exchange halves, select
    const unsigned c0 = pack2(p[0],  p[1]),  c1 = pack2(p[2],  p[3]);
    const unsigned c2 = pack2(p[4],  p[5]),  c3 = pack2(p[6],  p[7]);
    const unsigned c4 = pack2(p[8],  p[9]),  c5 = pack2(p[10], p[11]);
    const unsigned c6 = pack2(p[12], p[13]), c7 = pack2(p[14], p[15]);
    const unsigned x0 = __shfl_xor(c0, 32, 64), x1 = __shfl_xor(c1, 32, 64);
    const unsigned x2 = __shfl_xor(c2, 32, 64), x3 = __shfl_xor(c3, 32, 64);
    const unsigned x4 = __shfl_xor(c4, 32, 64), x5 = __shfl_xor(c5, 32, 64);
    const unsigned x6 = __shfl_xor(c6, 32, 64), x7 = __shfl_xor(c7, 32, 64);
    const bf16x8 pf0 = frag4(hi ? x2 : c0, hi ? x3 : c1, hi ? c2 : x0, hi ? c3 : x1);
    const bf16x8 pf1 = frag4(hi ? x6 : c4, hi ? x7 : c5, hi ? c6 : x4, hi ? c7 : x5);

    // O^T += V^T P^T   (A = V^T frag: row=d, depth=k; contiguous from Vt)
    bf16x8 va;
    va = *(const bf16x8*)(Vb + (size_t)l31 * 2048        + kv0 + hi * 8);
    o0 = MFMA32(va, pf0, o0);
    va = *(const bf16x8*)(Vb + (size_t)l31 * 2048        + kv0 + 16 + hi * 8);
    o0 = MFMA32(va, pf1, o0);
    va = *(const bf16x8*)(Vb + (size_t)(32 + l31) * 2048 + kv0 + hi * 8);
    o1 = MFMA32(va, pf0, o1);
    va = *(const bf16x8*)(Vb + (size_t)(32 + l31) * 2048 + kv0 + 16 + hi * 8);
    o1 = MFMA32(va, pf1, o1);
  }

  const float inv = 1.0f / L;
  const int b = bh >> 4, h = bh & 15;
  const int t = qs + l31;
  __bf16* orow = Oc + (size_t)(b * 2048 + t) * 1024 + h * 64;
#pragma unroll
  for (int q4 = 0; q4 < 4; ++q4) {
    bf16x4 v0, v1;
#pragma unroll
    for (int j = 0; j < 4; ++j) {
      v0[j] = (__bf16)(o0[q4 * 4 + j] * inv);
      v1[j] = (__bf16)(o1[q4 * 4 + j] * inv);
    }
    const int d0 = 8 * q4 + 4 * hi;
    *(bf16x4*)(orow + d0)      = v0;
    *(bf16x4*)(orow + 32 + d0) = v1;
  }
}

extern "C" void kernel_launch(void* const* d_in, const int* in_sizes, int n_in,
                              void* d_out, int out_size, void* d_ws, size_t ws_size,
                              hipStream_t stream) {
  const float* x  = (const float*)d_in[0];
  const float* Wq = (const float*)d_in[1];
  const float* bq = (const float*)d_in[2];
  const float* Wk = (const float*)d_in[3];
  const float* bk = (const float*)d_in[4];
  const float* Wv = (const float*)d_in[5];
  const float* bv = (const float*)d_in[6];
  const float* Wp = (const float*)d_in[7];
  const float* bp = (const float*)d_in[8];

  __bf16* Qw = (__bf16*)d_ws;                 // [32][2048][64]  8 MB
  __bf16* Kw = Qw + (size_t)4194304;          // [32][2048][64]  8 MB
  __bf16* Vw = Kw + (size_t)4194304;          // [32][64][2048]  8 MB (V^T)
  __bf16* Aw = Vw + (size_t)4194304;          // [4096][1024]    8 MB (attn out)

  dim3 bb(256);
  gemm_qkv_kernel<<<dim3(16, 64, 3), bb, 0, stream>>>(
      x, Wq, bq, Wk, bk, Wv, bv, Qw, Kw, Vw);
  attn_kernel<<<dim3(32, 16), bb, 0, stream>>>(Qw, Kw, Vw, Aw);
  gemm_proj_kernel<<<dim3(16, 64), bb, 0, stream>>>(Aw, Wp, bp, (float*)d_out);
}

// Round 4
// 174.965 us; speedup vs baseline: 1.8109x; 1.1398x over previous
//
#include <hip/hip_runtime.h>
#include <hip/hip_bf16.h>

typedef __bf16 bf16x8 __attribute__((ext_vector_type(8)));
typedef __bf16 bf16x4 __attribute__((ext_vector_type(4)));
typedef __bf16 bf16x2 __attribute__((ext_vector_type(2)));
typedef float  f32x4  __attribute__((ext_vector_type(4)));
typedef float  f32x16v __attribute__((ext_vector_type(16)));

#define MFMA16(A,B,Cc) __builtin_amdgcn_mfma_f32_16x16x32_bf16(A,B,Cc,0,0,0)
#define MFMA32(A,B,Cc) __builtin_amdgcn_mfma_f32_32x32x16_bf16(A,B,Cc,0,0,0)

__device__ inline bf16x8 load8f(const float* p) {
  const f32x4 a = *(const f32x4*)p;
  const f32x4 b = *(const f32x4*)(p + 4);
  bf16x8 r;
#pragma unroll
  for (int j = 0; j < 4; ++j) { r[j] = (__bf16)a[j]; r[j + 4] = (__bf16)b[j]; }
  return r;
}

__device__ inline unsigned pack2(float a, float b) {
  union { bf16x2 v; unsigned u; } t;
  t.v[0] = (__bf16)a; t.v[1] = (__bf16)b;
  return t.u;
}
__device__ inline bf16x8 frag4(unsigned w0, unsigned w1, unsigned w2, unsigned w3) {
  union { unsigned u[4]; bf16x8 v; } t;
  t.u[0] = w0; t.u[1] = w1; t.u[2] = w2; t.u[3] = w3;
  return t.v;
}

// ---------------- fused QKV GEMM:  out_z = x @ Wz^T + bz ----------------
// x: [4096][1024] f32.  z=0,1 -> Q/K scatter [BH][T][64]; z=2 -> V^T [BH][64][T].
__global__ __launch_bounds__(256) void gemm_qkv_kernel(
    const float* __restrict__ x,
    const float* __restrict__ Wq, const float* __restrict__ bq,
    const float* __restrict__ Wk, const float* __restrict__ bk,
    const float* __restrict__ Wv, const float* __restrict__ bv,
    __bf16* __restrict__ Qw, __bf16* __restrict__ Kw, __bf16* __restrict__ Vw)
{
  __shared__ __align__(16) __bf16 As[64 * 40];   // +8 pad: kills 8-way read conflict
  __shared__ __align__(16) __bf16 Bs[64 * 40];
  const int z = blockIdx.z;
  const float* W  = (z == 0) ? Wq : (z == 1) ? Wk : Wv;
  const float* bi = (z == 0) ? bq : (z == 1) ? bk : bv;
  __bf16* out     = (z == 0) ? Qw : (z == 1) ? Kw : Vw;

  const int tid = threadIdx.x, lane = tid & 63, wid = tid >> 6;
  const int wr = wid >> 1, wc = wid & 1;
  const int g = lane >> 4, cl = lane & 15;
  const int m0 = blockIdx.y * 64, n0 = blockIdx.x * 64;
  const int sr = tid >> 2, sk = (tid & 3) * 8;

  f32x4 acc[2][2] = {};
  for (int k0 = 0; k0 < 1024; k0 += 32) {
    bf16x8 a = load8f(x + (size_t)(m0 + sr) * 1024 + k0 + sk);
    bf16x8 b = load8f(W + (size_t)(n0 + sr) * 1024 + k0 + sk);
    __syncthreads();
    *(bf16x8*)(As + sr * 40 + sk) = a;
    *(bf16x8*)(Bs + sr * 40 + sk) = b;
    __syncthreads();
    bf16x8 af[2], bfr[2];
#pragma unroll
    for (int m = 0; m < 2; ++m)
      af[m] = *(const bf16x8*)(As + (wr * 32 + m * 16 + cl) * 40 + g * 8);
#pragma unroll
    for (int n = 0; n < 2; ++n)
      bfr[n] = *(const bf16x8*)(Bs + (wc * 32 + n * 16 + cl) * 40 + g * 8);
#pragma unroll
    for (int m = 0; m < 2; ++m)
#pragma unroll
      for (int n = 0; n < 2; ++n)
        acc[m][n] = MFMA16(af[m], bfr[n], acc[m][n]);
  }

  float bvv[2];
#pragma unroll
  for (int n = 0; n < 2; ++n) bvv[n] = bi[n0 + wc * 32 + n * 16 + cl];

#pragma unroll
  for (int m = 0; m < 2; ++m)
#pragma unroll
    for (int n = 0; n < 2; ++n) {
      const int col = n0 + wc * 32 + n * 16 + cl;
      const int h = col >> 6, d = col & 63;
      if (z == 2) {
        const int row0 = m0 + wr * 32 + m * 16 + g * 4;
        const int b2 = row0 >> 11, t0 = row0 & 2047;
        bf16x4 v4;
#pragma unroll
        for (int j = 0; j < 4; ++j) v4[j] = (__bf16)(acc[m][n][j] + bvv[n]);
        *(bf16x4*)(out + (size_t)(b2 * 16 + h) * 131072 + (size_t)d * 2048 + t0) = v4;
      } else {
#pragma unroll
        for (int j = 0; j < 4; ++j) {
          const int row = m0 + wr * 32 + m * 16 + g * 4 + j;
          const int b2 = row >> 11, t = row & 2047;
          out[(size_t)(b2 * 16 + h) * 131072 + (size_t)t * 64 + d] =
              (__bf16)(acc[m][n][j] + bvv[n]);
        }
      }
    }
}

// ---------------- projection GEMM: out = Aw @ Wp^T + bp (f32 out) ----------------
__global__ __launch_bounds__(256) void gemm_proj_kernel(
    const __bf16* __restrict__ A, const float* __restrict__ W,
    const float* __restrict__ bi, float* __restrict__ outp)
{
  __shared__ __align__(16) __bf16 As[64 * 40];
  __shared__ __align__(16) __bf16 Bs[64 * 40];
  const int tid = threadIdx.x, lane = tid & 63, wid = tid >> 6;
  const int wr = wid >> 1, wc = wid & 1;
  const int g = lane >> 4, cl = lane & 15;
  const int m0 = blockIdx.y * 64, n0 = blockIdx.x * 64;
  const int sr = tid >> 2, sk = (tid & 3) * 8;

  f32x4 acc[2][2] = {};
  for (int k0 = 0; k0 < 1024; k0 += 32) {
    bf16x8 a = *(const bf16x8*)(A + (size_t)(m0 + sr) * 1024 + k0 + sk);
    bf16x8 b = load8f(W + (size_t)(n0 + sr) * 1024 + k0 + sk);
    __syncthreads();
    *(bf16x8*)(As + sr * 40 + sk) = a;
    *(bf16x8*)(Bs + sr * 40 + sk) = b;
    __syncthreads();
    bf16x8 af[2], bfr[2];
#pragma unroll
    for (int m = 0; m < 2; ++m)
      af[m] = *(const bf16x8*)(As + (wr * 32 + m * 16 + cl) * 40 + g * 8);
#pragma unroll
    for (int n = 0; n < 2; ++n)
      bfr[n] = *(const bf16x8*)(Bs + (wc * 32 + n * 16 + cl) * 40 + g * 8);
#pragma unroll
    for (int m = 0; m < 2; ++m)
#pragma unroll
      for (int n = 0; n < 2; ++n)
        acc[m][n] = MFMA16(af[m], bfr[n], acc[m][n]);
  }

  float bvv[2];
#pragma unroll
  for (int n = 0; n < 2; ++n) bvv[n] = bi[n0 + wc * 32 + n * 16 + cl];
#pragma unroll
  for (int m = 0; m < 2; ++m)
#pragma unroll
    for (int n = 0; n < 2; ++n) {
      const int col = n0 + wc * 32 + n * 16 + cl;
#pragma unroll
      for (int j = 0; j < 4; ++j) {
        const int row = m0 + wr * 32 + m * 16 + g * 4 + j;
        outp[(size_t)row * 1024 + col] = acc[m][n][j] + bvv[n];
      }
    }
}

// ---------------- causal flash attention, swapped-QK 32x32, KV-split x2 ----------------
// Q,K: [BH][T][64]; Vt: [BH][64][T]; out Aw: [B*T][1024], all bf16.
// Block = 128 threads = 2 waves; both waves own the same 32-row q-strip but
// disjoint halves of its kv-range; merged via LDS online-softmax combine.
__global__ __launch_bounds__(128, 4) void attn_kernel(
    const __bf16* __restrict__ Q, const __bf16* __restrict__ K,
    const __bf16* __restrict__ Vt, __bf16* __restrict__ Oc)
{
  const int bh    = blockIdx.x;
  const int strip = 63 - (int)blockIdx.y;       // long strips dispatch first
  const int wid   = threadIdx.x >> 6;
  const int lane  = threadIdx.x & 63;
  const int l31 = lane & 31, hi = lane >> 5;
  const int qs = strip * 32;

  const __bf16* Qb = Q  + (size_t)bh * 131072;
  const __bf16* Kb = K  + (size_t)bh * 131072;
  const __bf16* Vb = Vt + (size_t)bh * 131072;

  const int ntiles = strip + 1;                 // 32-kv tiles in [0, qs]
  const int nA   = (ntiles + 1) >> 1;
  const int tBeg = wid ? nA : 0;
  const int tEnd = wid ? ntiles : nA;

  bf16x8 qf[4];
#pragma unroll
  for (int c = 0; c < 4; ++c)
    qf[c] = *(const bf16x8*)(Qb + (qs + l31) * 64 + c * 16 + hi * 8);

  f32x16v o0 = {}, o1 = {};
  float M = -1e30f, L = 0.f;
  const float SC = 0.18033688f;                 // 0.125 * log2(e)

  const __bf16* vrow0 = Vb + (size_t)l31 * 2048;
  const __bf16* vrow1 = Vb + (size_t)(32 + l31) * 2048;

  for (int t = tBeg; t < tEnd; ++t) {
    const int kv0 = t * 32;
    f32x16v s = {};
#pragma unroll
    for (int c = 0; c < 4; ++c) {
      bf16x8 kf = *(const bf16x8*)(Kb + (kv0 + l31) * 64 + c * 16 + hi * 8);
      s = MFMA32(kf, qf[c], s);
    }
    float sv[16];
#pragma unroll
    for (int r = 0; r < 16; ++r) sv[r] = s[r];
    if (t == ntiles - 1) {                      // globally-last tile: mask k > q
#pragma unroll
      for (int r = 0; r < 16; ++r) {
        const int kl = (r & 3) + 8 * (r >> 2) + 4 * hi;
        if (kl > l31) sv[r] = -1e30f;
      }
    }
    float mt = sv[0];
#pragma unroll
    for (int r = 1; r < 16; ++r) mt = fmaxf(mt, sv[r]);
    mt = fmaxf(mt, __shfl_xor(mt, 32, 64));
    if (!__all(mt <= M)) {                      // defer-max: rescale only on growth
      const float Mn = fmaxf(M, mt);
      const float rs = exp2f((M - Mn) * SC);
      o0 *= rs; o1 *= rs; L *= rs; M = Mn;
    }
    float p[16];
    float lt = 0.f;
#pragma unroll
    for (int r = 0; r < 16; ++r) { p[r] = exp2f((sv[r] - M) * SC); lt += p[r]; }
    lt += __shfl_xor(lt, 32, 64);
    L += lt;

    const unsigned c0 = pack2(p[0],  p[1]),  c1 = pack2(p[2],  p[3]);
    const unsigned c2 = pack2(p[4],  p[5]),  c3 = pack2(p[6],  p[7]);
    const unsigned c4 = pack2(p[8],  p[9]),  c5 = pack2(p[10], p[11]);
    const unsigned c6 = pack2(p[12], p[13]), c7 = pack2(p[14], p[15]);
    const unsigned x0 = __shfl_xor(c0, 32, 64), x1 = __shfl_xor(c1, 32, 64);
    const unsigned x2 = __shfl_xor(c2, 32, 64), x3 = __shfl_xor(c3, 32, 64);
    const unsigned x4 = __shfl_xor(c4, 32, 64), x5 = __shfl_xor(c5, 32, 64);
    const unsigned x6 = __shfl_xor(c6, 32, 64), x7 = __shfl_xor(c7, 32, 64);
    const bf16x8 pf0 = frag4(hi ? x2 : c0, hi ? x3 : c1, hi ? c2 : x0, hi ? c3 : x1);
    const bf16x8 pf1 = frag4(hi ? x6 : c4, hi ? x7 : c5, hi ? c6 : x4, hi ? c7 : x5);

    bf16x8 va;
    va = *(const bf16x8*)(vrow0 + kv0 + hi * 8);       o0 = MFMA32(va, pf0, o0);
    va = *(const bf16x8*)(vrow0 + kv0 + 16 + hi * 8);  o0 = MFMA32(va, pf1, o0);
    va = *(const bf16x8*)(vrow1 + kv0 + hi * 8);       o1 = MFMA32(va, pf0, o1);
    va = *(const bf16x8*)(vrow1 + kv0 + 16 + hi * 8);  o1 = MFMA32(va, pf1, o1);
  }

  // ---- merge the two kv-halves through LDS ----
  __shared__ float Sm[64][34];
  if (wid == 1) {
#pragma unroll
    for (int q4 = 0; q4 < 4; ++q4) {
      f32x4 a = { o0[q4*4+0], o0[q4*4+1], o0[q4*4+2], o0[q4*4+3] };
      f32x4 b = { o1[q4*4+0], o1[q4*4+1], o1[q4*4+2], o1[q4*4+3] };
      *(f32x4*)&Sm[lane][q4 * 4]      = a;
      *(f32x4*)&Sm[lane][16 + q4 * 4] = b;
    }
    Sm[lane][32] = M;
    Sm[lane][33] = L;
  }
  __syncthreads();
  if (wid == 0) {
    const float M1 = Sm[lane][32];
    const float L1 = Sm[lane][33];
    const float Ms = fmaxf(M, M1);
    const float r0 = exp2f((M  - Ms) * SC);
    const float r1 = exp2f((M1 - Ms) * SC);
    const float inv = 1.0f / (L * r0 + L1 * r1);

    const int b = bh >> 4, h = bh & 15;
    const int tq = qs + l31;
    __bf16* orow = Oc + (size_t)(b * 2048 + tq) * 1024 + h * 64;
#pragma unroll
    for (int q4 = 0; q4 < 4; ++q4) {
      bf16x4 v0, v1;
#pragma unroll
      for (int j = 0; j < 4; ++j) {
        const int r = q4 * 4 + j;
        v0[j] = (__bf16)((o0[r] * r0 + Sm[lane][r]      * r1) * inv);
        v1[j] = (__bf16)((o1[r] * r0 + Sm[lane][16 + r] * r1) * inv);
      }
      const int d0 = 8 * q4 + 4 * hi;
      *(bf16x4*)(orow + d0)      = v0;
      *(bf16x4*)(orow + 32 + d0) = v1;
    }
  }
}

extern "C" void kernel_launch(void* const* d_in, const int* in_sizes, int n_in,
                              void* d_out, int out_size, void* d_ws, size_t ws_size,
                              hipStream_t stream) {
  const float* x  = (const float*)d_in[0];
  const float* Wq = (const float*)d_in[1];
  const float* bq = (const float*)d_in[2];
  const float* Wk = (const float*)d_in[3];
  const float* bk = (const float*)d_in[4];
  const float* Wv = (const float*)d_in[5];
  const float* bv = (const float*)d_in[6];
  const float* Wp = (const float*)d_in[7];
  const float* bp = (const float*)d_in[8];

  __bf16* Qw = (__bf16*)d_ws;                 // [32][2048][64]  8 MB
  __bf16* Kw = Qw + (size_t)4194304;          // [32][2048][64]  8 MB
  __bf16* Vw = Kw + (size_t)4194304;          // [32][64][2048]  8 MB (V^T)
  __bf16* Aw = Vw + (size_t)4194304;          // [4096][1024]    8 MB (attn out)

  gemm_qkv_kernel<<<dim3(16, 64, 3), 256, 0, stream>>>(
      x, Wq, bq, Wk, bk, Wv, bv, Qw, Kw, Vw);
  attn_kernel<<<dim3(32, 64), 128, 0, stream>>>(Qw, Kw, Vw, Aw);
  gemm_proj_kernel<<<dim3(16, 64), 256, 0, stream>>>(Aw, Wp, bp, (float*)d_out);
}

// Round 5
// 145.386 us; speedup vs baseline: 2.1793x; 1.2034x over previous
//
#include <hip/hip_runtime.h>
#include <hip/hip_bf16.h>

typedef __bf16 bf16x8 __attribute__((ext_vector_type(8)));
typedef __bf16 bf16x4 __attribute__((ext_vector_type(4)));
typedef __bf16 bf16x2 __attribute__((ext_vector_type(2)));
typedef float  f32x4  __attribute__((ext_vector_type(4)));
typedef float  f32x16v __attribute__((ext_vector_type(16)));

#define MFMA16(A,B,Cc) __builtin_amdgcn_mfma_f32_16x16x32_bf16(A,B,Cc,0,0,0)
#define MFMA32(A,B,Cc) __builtin_amdgcn_mfma_f32_32x32x16_bf16(A,B,Cc,0,0,0)

__device__ inline unsigned pack2(float a, float b) {
  union { bf16x2 v; unsigned u; } t;
  t.v[0] = (__bf16)a; t.v[1] = (__bf16)b;
  return t.u;
}
__device__ inline bf16x8 frag4(unsigned w0, unsigned w1, unsigned w2, unsigned w3) {
  union { unsigned u[4]; bf16x8 v; } t;
  t.u[0] = w0; t.u[1] = w1; t.u[2] = w2; t.u[3] = w3;
  return t.v;
}

// ---------------- f32 -> bf16 pre-convert (x + 4 weight matrices) ----------------
__global__ __launch_bounds__(256) void conv_kernel(
    const float* __restrict__ x,
    const float* __restrict__ Wq, const float* __restrict__ Wk,
    const float* __restrict__ Wv, const float* __restrict__ Wp,
    __bf16* __restrict__ xb, __bf16* __restrict__ Wb)
{
  const int z = blockIdx.y;
  const float* src;
  __bf16* dst;
  int n4;
  if (z == 0) { src = x;  dst = xb; n4 = 1048576; }
  else {
    src = (z == 1) ? Wq : (z == 2) ? Wk : (z == 3) ? Wv : Wp;
    dst = Wb + (size_t)(z - 1) * 1048576;
    n4  = 262144;
  }
  const f32x4* s4 = (const f32x4*)src;
  for (int i = blockIdx.x * 256 + threadIdx.x; i < n4; i += gridDim.x * 256) {
    const f32x4 v = s4[i];
    bf16x4 o;
#pragma unroll
    for (int j = 0; j < 4; ++j) o[j] = (__bf16)v[j];
    *(bf16x4*)(dst + (size_t)i * 4) = o;
  }
}

// ---------------- shared 128x128x(K=1024) bf16 MFMA core ----------------
__device__ inline void gemm_core(const __bf16* __restrict__ A,
                                 const __bf16* __restrict__ W,
                                 int m0, int n0,
                                 __bf16* As, __bf16* Bs,
                                 f32x4 (&acc)[4][4])
{
  const int tid = threadIdx.x, lane = tid & 63;
  const int wid = tid >> 6, wr = wid >> 1, wc = wid & 1;
  const int g = lane >> 4, cl = lane & 15;
  const int sr = tid >> 2, sk = (tid & 3) * 8;

  for (int k0 = 0; k0 < 1024; k0 += 32) {
    bf16x8 a0 = *(const bf16x8*)(A + (size_t)(m0 + sr)      * 1024 + k0 + sk);
    bf16x8 a1 = *(const bf16x8*)(A + (size_t)(m0 + sr + 64) * 1024 + k0 + sk);
    bf16x8 b0 = *(const bf16x8*)(W + (size_t)(n0 + sr)      * 1024 + k0 + sk);
    bf16x8 b1 = *(const bf16x8*)(W + (size_t)(n0 + sr + 64) * 1024 + k0 + sk);
    __syncthreads();
    *(bf16x8*)(As + sr * 32 + sk)        = a0;
    *(bf16x8*)(As + (sr + 64) * 32 + sk) = a1;
    *(bf16x8*)(Bs + sr * 32 + sk)        = b0;
    *(bf16x8*)(Bs + (sr + 64) * 32 + sk) = b1;
    __syncthreads();
    bf16x8 af[4], bfr[4];
#pragma unroll
    for (int m = 0; m < 4; ++m)
      af[m] = *(const bf16x8*)(As + (wr * 64 + m * 16 + cl) * 32 + g * 8);
#pragma unroll
    for (int n = 0; n < 4; ++n)
      bfr[n] = *(const bf16x8*)(Bs + (wc * 64 + n * 16 + cl) * 32 + g * 8);
#pragma unroll
    for (int m = 0; m < 4; ++m)
#pragma unroll
      for (int n = 0; n < 4; ++n)
        acc[m][n] = MFMA16(af[m], bfr[n], acc[m][n]);
  }
}

// ---------------- fused QKV GEMM (bf16 in, scattered bf16 out) ----------------
// 768 wgs, XCD-chunked: each XCD gets 96 consecutive wgids (12 m-panels x 8 n, one z).
__global__ __launch_bounds__(256) void gemm_qkv128(
    const __bf16* __restrict__ xb, const __bf16* __restrict__ Wb,
    const float* __restrict__ bq, const float* __restrict__ bk,
    const float* __restrict__ bv,
    __bf16* __restrict__ Qw, __bf16* __restrict__ Kw, __bf16* __restrict__ Vw)
{
  __shared__ __align__(16) __bf16 As[128 * 32];
  __shared__ __align__(16) __bf16 Bs[128 * 32];

  const int orig = blockIdx.x;
  const int wg   = (orig & 7) * 96 + (orig >> 3);   // bijective: 768 = 8*96
  const int z    = wg >> 8;
  const int rem  = wg & 255;
  const int m0   = (rem >> 3) * 128;
  const int n0   = (rem & 7) * 128;

  const __bf16* W  = Wb + (size_t)z * 1048576;
  const float*  bi = (z == 0) ? bq : (z == 1) ? bk : bv;
  __bf16*       out = (z == 0) ? Qw : (z == 1) ? Kw : Vw;

  f32x4 acc[4][4] = {};
  gemm_core(xb, W, m0, n0, As, Bs, acc);

  const int lane = threadIdx.x & 63, wid = threadIdx.x >> 6;
  const int wr = wid >> 1, wc = wid & 1;
  const int g = lane >> 4, cl = lane & 15;

  float bvv[4];
#pragma unroll
  for (int n = 0; n < 4; ++n) bvv[n] = bi[n0 + wc * 64 + n * 16 + cl];

#pragma unroll
  for (int m = 0; m < 4; ++m)
#pragma unroll
    for (int n = 0; n < 4; ++n) {
      const int col = n0 + wc * 64 + n * 16 + cl;
      const int h = col >> 6, d = col & 63;
      if (z == 2) {                               // V^T scatter [BH][D][T]
        const int row0 = m0 + wr * 64 + m * 16 + g * 4;
        const int b2 = row0 >> 11, t0 = row0 & 2047;
        bf16x4 v4;
#pragma unroll
        for (int j = 0; j < 4; ++j) v4[j] = (__bf16)(acc[m][n][j] + bvv[n]);
        *(bf16x4*)(out + (size_t)(b2 * 16 + h) * 131072 + (size_t)d * 2048 + t0) = v4;
      } else {                                    // Q/K scatter [BH][T][D]
#pragma unroll
        for (int j = 0; j < 4; ++j) {
          const int row = m0 + wr * 64 + m * 16 + g * 4 + j;
          const int b2 = row >> 11, t = row & 2047;
          out[(size_t)(b2 * 16 + h) * 131072 + (size_t)t * 64 + d] =
              (__bf16)(acc[m][n][j] + bvv[n]);
        }
      }
    }
}

// ---------------- projection GEMM (bf16 in, f32 out) ----------------
__global__ __launch_bounds__(256) void gemm_proj128(
    const __bf16* __restrict__ A, const __bf16* __restrict__ W,
    const float* __restrict__ bi, float* __restrict__ outp)
{
  __shared__ __align__(16) __bf16 As[128 * 32];
  __shared__ __align__(16) __bf16 Bs[128 * 32];

  const int orig = blockIdx.x;
  const int wg   = (orig & 7) * 32 + (orig >> 3);   // bijective: 256 = 8*32
  const int m0   = (wg >> 3) * 128;
  const int n0   = (wg & 7) * 128;

  f32x4 acc[4][4] = {};
  gemm_core(A, W, m0, n0, As, Bs, acc);

  const int lane = threadIdx.x & 63, wid = threadIdx.x >> 6;
  const int wr = wid >> 1, wc = wid & 1;
  const int g = lane >> 4, cl = lane & 15;

  float bvv[4];
#pragma unroll
  for (int n = 0; n < 4; ++n) bvv[n] = bi[n0 + wc * 64 + n * 16 + cl];
#pragma unroll
  for (int m = 0; m < 4; ++m)
#pragma unroll
    for (int n = 0; n < 4; ++n) {
      const int col = n0 + wc * 64 + n * 16 + cl;
#pragma unroll
      for (int j = 0; j < 4; ++j) {
        const int row = m0 + wr * 64 + m * 16 + g * 4 + j;
        outp[(size_t)row * 1024 + col] = acc[m][n][j] + bvv[n];
      }
    }
}

// ---------------- causal flash attention, swapped-QK 32x32, KV-split x2 ----------------
__global__ __launch_bounds__(128, 4) void attn_kernel(
    const __bf16* __restrict__ Q, const __bf16* __restrict__ K,
    const __bf16* __restrict__ Vt, __bf16* __restrict__ Oc)
{
  const int bh    = blockIdx.x;
  const int strip = 63 - (int)blockIdx.y;       // long strips dispatch first
  const int wid   = threadIdx.x >> 6;
  const int lane  = threadIdx.x & 63;
  const int l31 = lane & 31, hi = lane >> 5;
  const int qs = strip * 32;

  const __bf16* Qb = Q  + (size_t)bh * 131072;
  const __bf16* Kb = K  + (size_t)bh * 131072;
  const __bf16* Vb = Vt + (size_t)bh * 131072;

  const int ntiles = strip + 1;
  const int nA   = (ntiles + 1) >> 1;
  const int tBeg = wid ? nA : 0;
  const int tEnd = wid ? ntiles : nA;

  bf16x8 qf[4];
#pragma unroll
  for (int c = 0; c < 4; ++c)
    qf[c] = *(const bf16x8*)(Qb + (qs + l31) * 64 + c * 16 + hi * 8);

  f32x16v o0 = {}, o1 = {};
  float M = -1e30f, L = 0.f;
  const float SC = 0.18033688f;                 // 0.125 * log2(e)

  const __bf16* vrow0 = Vb + (size_t)l31 * 2048;
  const __bf16* vrow1 = Vb + (size_t)(32 + l31) * 2048;

  for (int t = tBeg; t < tEnd; ++t) {
    const int kv0 = t * 32;
    f32x16v s = {};
#pragma unroll
    for (int c = 0; c < 4; ++c) {
      bf16x8 kf = *(const bf16x8*)(Kb + (kv0 + l31) * 64 + c * 16 + hi * 8);
      s = MFMA32(kf, qf[c], s);
    }
    float sv[16];
#pragma unroll
    for (int r = 0; r < 16; ++r) sv[r] = s[r];
    if (t == ntiles - 1) {
#pragma unroll
      for (int r = 0; r < 16; ++r) {
        const int kl = (r & 3) + 8 * (r >> 2) + 4 * hi;
        if (kl > l31) sv[r] = -1e30f;
      }
    }
    float mt = sv[0];
#pragma unroll
    for (int r = 1; r < 16; ++r) mt = fmaxf(mt, sv[r]);
    mt = fmaxf(mt, __shfl_xor(mt, 32, 64));
    if (!__all(mt <= M)) {
      const float Mn = fmaxf(M, mt);
      const float rs = exp2f((M - Mn) * SC);
      o0 *= rs; o1 *= rs; L *= rs; M = Mn;
    }
    float p[16];
    float lt = 0.f;
#pragma unroll
    for (int r = 0; r < 16; ++r) { p[r] = exp2f((sv[r] - M) * SC); lt += p[r]; }
    lt += __shfl_xor(lt, 32, 64);
    L += lt;

    const unsigned c0 = pack2(p[0],  p[1]),  c1 = pack2(p[2],  p[3]);
    const unsigned c2 = pack2(p[4],  p[5]),  c3 = pack2(p[6],  p[7]);
    const unsigned c4 = pack2(p[8],  p[9]),  c5 = pack2(p[10], p[11]);
    const unsigned c6 = pack2(p[12], p[13]), c7 = pack2(p[14], p[15]);
    const unsigned x0 = __shfl_xor(c0, 32, 64), x1 = __shfl_xor(c1, 32, 64);
    const unsigned x2 = __shfl_xor(c2, 32, 64), x3 = __shfl_xor(c3, 32, 64);
    const unsigned x4 = __shfl_xor(c4, 32, 64), x5 = __shfl_xor(c5, 32, 64);
    const unsigned x6 = __shfl_xor(c6, 32, 64), x7 = __shfl_xor(c7, 32, 64);
    const bf16x8 pf0 = frag4(hi ? x2 : c0, hi ? x3 : c1, hi ? c2 : x0, hi ? c3 : x1);
    const bf16x8 pf1 = frag4(hi ? x6 : c4, hi ? x7 : c5, hi ? c6 : x4, hi ? c7 : x5);

    bf16x8 va;
    va = *(const bf16x8*)(vrow0 + kv0 + hi * 8);       o0 = MFMA32(va, pf0, o0);
    va = *(const bf16x8*)(vrow0 + kv0 + 16 + hi * 8);  o0 = MFMA32(va, pf1, o0);
    va = *(const bf16x8*)(vrow1 + kv0 + hi * 8);       o1 = MFMA32(va, pf0, o1);
    va = *(const bf16x8*)(vrow1 + kv0 + 16 + hi * 8);  o1 = MFMA32(va, pf1, o1);
  }

  __shared__ float Sm[64][34];
  if (wid == 1) {
#pragma unroll
    for (int q4 = 0; q4 < 4; ++q4) {
      f32x4 a = { o0[q4*4+0], o0[q4*4+1], o0[q4*4+2], o0[q4*4+3] };
      f32x4 b = { o1[q4*4+0], o1[q4*4+1], o1[q4*4+2], o1[q4*4+3] };
      *(f32x4*)&Sm[lane][q4 * 4]      = a;
      *(f32x4*)&Sm[lane][16 + q4 * 4] = b;
    }
    Sm[lane][32] = M;
    Sm[lane][33] = L;
  }
  __syncthreads();
  if (wid == 0) {
    const float M1 = Sm[lane][32];
    const float L1 = Sm[lane][33];
    const float Ms = fmaxf(M, M1);
    const float r0 = exp2f((M  - Ms) * SC);
    const float r1 = exp2f((M1 - Ms) * SC);
    const float inv = 1.0f / (L * r0 + L1 * r1);

    const int b = bh >> 4, h = bh & 15;
    const int tq = qs + l31;
    __bf16* orow = Oc + (size_t)(b * 2048 + tq) * 1024 + h * 64;
#pragma unroll
    for (int q4 = 0; q4 < 4; ++q4) {
      bf16x4 v0, v1;
#pragma unroll
      for (int j = 0; j < 4; ++j) {
        const int r = q4 * 4 + j;
        v0[j] = (__bf16)((o0[r] * r0 + Sm[lane][r]      * r1) * inv);
        v1[j] = (__bf16)((o1[r] * r0 + Sm[lane][16 + r] * r1) * inv);
      }
      const int d0 = 8 * q4 + 4 * hi;
      *(bf16x4*)(orow + d0)      = v0;
      *(bf16x4*)(orow + 32 + d0) = v1;
    }
  }
}

extern "C" void kernel_launch(void* const* d_in, const int* in_sizes, int n_in,
                              void* d_out, int out_size, void* d_ws, size_t ws_size,
                              hipStream_t stream) {
  const float* x  = (const float*)d_in[0];
  const float* Wq = (const float*)d_in[1];
  const float* bq = (const float*)d_in[2];
  const float* Wk = (const float*)d_in[3];
  const float* bk = (const float*)d_in[4];
  const float* Wv = (const float*)d_in[5];
  const float* bv = (const float*)d_in[6];
  const float* Wp = (const float*)d_in[7];
  const float* bp = (const float*)d_in[8];

  __bf16* Qw  = (__bf16*)d_ws;                 // [32][2048][64]  8 MB
  __bf16* Kw  = Qw + (size_t)4194304;          // [32][2048][64]  8 MB
  __bf16* Vw  = Kw + (size_t)4194304;          // [32][64][2048]  8 MB (V^T)
  __bf16* xbA = Vw + (size_t)4194304;          // 8 MB: xb, then reused as Aw
  __bf16* Wb  = xbA + (size_t)4194304;         // [4][1024][1024] 8 MB bf16 weights

  conv_kernel<<<dim3(512, 5), 256, 0, stream>>>(x, Wq, Wk, Wv, Wp, xbA, Wb);
  gemm_qkv128<<<768, 256, 0, stream>>>(xbA, Wb, bq, bk, bv, Qw, Kw, Vw);
  attn_kernel<<<dim3(32, 64), 128, 0, stream>>>(Qw, Kw, Vw, xbA /*Aw*/);
  gemm_proj128<<<256, 256, 0, stream>>>(xbA /*Aw*/, Wb + (size_t)3 * 1048576,
                                        bp, (float*)d_out);
}